// Round 20
// baseline (457.263 us; speedup 1.0000x reference)
//
#include <hip/hip_runtime.h>
#include <hip/hip_bf16.h>
#include <cstdint>
#include <cstddef>

typedef __attribute__((ext_vector_type(8))) short bf16x8;
typedef __attribute__((ext_vector_type(4))) float f32x4;
typedef __attribute__((ext_vector_type(16))) float f32x16;

__device__ __forceinline__ unsigned short f2bf(float f) {
  union { float f; unsigned u; } c; c.f = f;
  unsigned r = c.u + 0x7FFFu + ((c.u >> 16) & 1u);
  return (unsigned short)(r >> 16);
}

__device__ __forceinline__ float bf2f(unsigned short u) {
  union { unsigned u; float f; } c; c.u = ((unsigned)u) << 16;
  return c.f;
}

__device__ __forceinline__ unsigned cvtpk(float lo, float hi) {
  unsigned r;
  asm("v_cvt_pk_bf16_f32 %0, %1, %2" : "=v"(r) : "v"(lo), "v"(hi));
  return r;
}

__device__ __forceinline__ float gelu_fast(float v) {
  const float u = v * (0.7978845608f + 0.0356774081f * v * v);
  const float a = fminf(-2.8853900818f * u, 80.0f);
  return v / (1.0f + exp2f(a));
}

__device__ __forceinline__ int xcd_swz(int bid, int nwg) {
  const int cpx = nwg >> 3;  // all grids here are %8==0
  return (bid & 7) * cpx + (bid >> 3);
}

typedef const __attribute__((address_space(1))) unsigned int* gas_ptr;
typedef __attribute__((address_space(3))) unsigned int* las_ptr;

__device__ __forceinline__ void gload16(const unsigned short* g, unsigned short* l) {
  __builtin_amdgcn_global_load_lds((gas_ptr)g, (las_ptr)l, 16, 0, 0);
}

// ---------------------------------------------------------------- fused weight convert
struct WJ { const float* s; unsigned short* d; int nblk; };
struct WJobs { WJ j[10]; };

__global__ void wconv_k(WJobs jb) {
  const int bid = blockIdx.x;
  int base = 0, ji = -1;
  #pragma unroll
  for (int k = 0; k < 10; ++k) {
    const int nb = jb.j[k].nblk;
    if (ji < 0) { if (bid < base + nb) ji = k; else base += nb; }
  }
  const int i = (bid - base) * 256 + threadIdx.x;
  float4 v = ((const float4*)jb.j[ji].s)[i];
  ushort4 o;
  o.x = f2bf(v.x); o.y = f2bf(v.y); o.z = f2bf(v.z); o.w = f2bf(v.w);
  ((ushort4*)jb.j[ji].d)[i] = o;
}

// context [4][77][768] fp32 -> padded [4][128][768] bf16 (pad rows = 0)
__global__ void ctxpad_k(const float* __restrict__ ctx, unsigned short* __restrict__ out) {
  int i = blockIdx.x * blockDim.x + threadIdx.x;
  if (i >= 512 * 192) return;
  int r = i / 192, c4 = i % 192;
  int b = r >> 7, s = r & 127;
  ushort4 o = {0, 0, 0, 0};
  if (s < 77) {
    float4 v = ((const float4*)(ctx + (size_t)(b * 77 + s) * 768))[c4];
    o.x = f2bf(v.x); o.y = f2bf(v.y); o.z = f2bf(v.z); o.w = f2bf(v.w);
  }
  ((ushort4*)out)[i] = o;
}

// ---------------------------------------------------------------- layernorm (INBF: 0=fp32 in, 1=bf16 in)
template<int INBF>
__global__ __launch_bounds__(256)
void ln_k(const void* __restrict__ xin, const float* __restrict__ w,
          const float* __restrict__ b, unsigned short* __restrict__ out) {
  int row = blockIdx.x, tid = threadIdx.x;
  float4 v;
  if constexpr (INBF) {
    ushort4 u = ((const ushort4*)((const unsigned short*)xin + (size_t)row * 1024))[tid];
    v.x = bf2f(u.x); v.y = bf2f(u.y); v.z = bf2f(u.z); v.w = bf2f(u.w);
  } else {
    v = ((const float4*)((const float*)xin + (size_t)row * 1024))[tid];
  }
  float s = v.x + v.y + v.z + v.w;
  float s2 = v.x * v.x + v.y * v.y + v.z * v.z + v.w * v.w;
  #pragma unroll
  for (int m = 1; m < 64; m <<= 1) { s += __shfl_xor(s, m); s2 += __shfl_xor(s2, m); }
  __shared__ float ps[4], ps2[4];
  int wv = tid >> 6;
  if ((tid & 63) == 0) { ps[wv] = s; ps2[wv] = s2; }
  __syncthreads();
  s = ps[0] + ps[1] + ps[2] + ps[3];
  s2 = ps2[0] + ps2[1] + ps2[2] + ps2[3];
  float mu = s * (1.0f / 1024.0f);
  float var = s2 * (1.0f / 1024.0f) - mu * mu;
  float rstd = rsqrtf(var + 1e-5f);
  float4 wv4 = ((const float4*)w)[tid];
  float4 bv4 = ((const float4*)b)[tid];
  ushort4 o;
  o.x = f2bf((v.x - mu) * rstd * wv4.x + bv4.x);
  o.y = f2bf((v.y - mu) * rstd * wv4.y + bv4.y);
  o.z = f2bf((v.z - mu) * rstd * wv4.z + bv4.z);
  o.w = f2bf((v.w - mu) * rstd * wv4.w + bv4.w);
  ((ushort4*)(out + (size_t)row * 1024))[tid] = o;
}

// ---------------------------------------------------------------- GEMM 8-phase
// PIPE=0: r13 structure (verified best for 256^2 / 1 block/CU).
// PIPE=1: r11 pipelined structure (128^2, 2 blocks/CU; fits 128-VGPR budget).
// EPI: 0=(acc+bias)*scale->bf16 (col-split C0/C1), 1=V^T pack (SWAP=0),
//      3=gelu->bf16, 4=col-split K/V (SWAP=0),
//      5=acc+bias+res(fp32)->bf16, 6=acc+bias+res(bf16)->bf16,
//      7=acc+bias+res(bf16)->fp32,
//      8=QKV fused (SWAP=1): seg0 Q*scale->C0, seg1 K->C1, seg2 V^T pack->C2
#define SG_A(BUF, H, TE)                                                       \
  _Pragma("unroll")                                                            \
  for (int j = 0; j < AHL; ++j)                                                \
    __builtin_amdgcn_global_load_lds(                                          \
        (gas_ptr)(gA + (TE) + (size_t)((H) * (BM / 2) + j * 64) * (size_t)K),  \
        (las_ptr)(lds_all + (BUF) * AELEMS +                                   \
                  (((H) * (BM / 2) + j * 64) + w * 8) * 64),                   \
        16, 0, 0);

#define SG_B(BUF, H, TE)                                                       \
  _Pragma("unroll")                                                            \
  for (int j = 0; j < BHL; ++j)                                                \
    __builtin_amdgcn_global_load_lds(                                          \
        (gas_ptr)(gB + (TE) + (size_t)((H) * (BN / 2) + j * 64) * (size_t)K),  \
        (las_ptr)(lds_all + 2 * AELEMS + (BUF) * BELEMS +                      \
                  (((H) * (BN / 2) + j * 64) + w * 8) * 64),                   \
        16, 0, 0);

#define RD_A(D, MHh, BUF)                                                      \
  _Pragma("unroll")                                                            \
  for (int i = 0; i < MH; ++i) {                                               \
    const int r = ((MHh) * MH + i) * 32 + wr * 16 + ln;                        \
    _Pragma("unroll")                                                          \
    for (int kc = 0; kc < 2; ++kc)                                             \
      af[D][i][kc] = *(const bf16x8*)((const char*)lds_all + (BUF) * ABYTES +  \
                    r * 128 + (((kc * 4 + lg) ^ (r & 7)) * 16));               \
  }

#define RD_B(NHh, BUF)                                                         \
  _Pragma("unroll")                                                            \
  for (int i = 0; i < NIH; ++i) {                                              \
    const int ni = (NHh) * NIH + i;                                            \
    const int r = ni * 64 + wcc * 16 + ln;                                     \
    _Pragma("unroll")                                                          \
    for (int kc = 0; kc < 2; ++kc)                                             \
      bfr[ni][kc] = *(const bf16x8*)((const char*)lds_all + 2 * ABYTES +       \
                    (BUF) * BBYTES + r * 128 + (((kc * 4 + lg) ^ (r & 7)) * 16)); \
  }

#define QUAD(D, MHh, NHh)                                                      \
  __builtin_amdgcn_s_setprio(1);                                               \
  _Pragma("unroll")                                                            \
  for (int kc = 0; kc < 2; ++kc)                                               \
    _Pragma("unroll")                                                          \
    for (int i = 0; i < MH; ++i)                                               \
      _Pragma("unroll")                                                        \
      for (int j2 = 0; j2 < NIH; ++j2) {                                       \
        const int mi = (MHh) * MH + i, ni = (NHh) * NIH + j2;                  \
        if constexpr (SWAP)                                                    \
          acc[mi][ni] = __builtin_amdgcn_mfma_f32_16x16x32_bf16(               \
              bfr[ni][kc], af[D][i][kc], acc[mi][ni], 0, 0, 0);                \
        else                                                                   \
          acc[mi][ni] = __builtin_amdgcn_mfma_f32_16x16x32_bf16(               \
              af[D][i][kc], bfr[ni][kc], acc[mi][ni], 0, 0, 0);                \
      }                                                                        \
  __builtin_amdgcn_s_setprio(0);

#define VM_PRO()                                                               \
  do { if constexpr (BM == 256) asm volatile("s_waitcnt vmcnt(6)" ::: "memory"); \
       else                     asm volatile("s_waitcnt vmcnt(3)" ::: "memory"); } while (0)

#define LGK0()                                                                 \
  asm volatile("s_waitcnt lgkmcnt(0)" ::: "memory");                           \
  __builtin_amdgcn_sched_barrier(0);

// r13 non-pipelined tile (for 256^2)
#define TILE_NP(BUF, TE)                                                       \
  {                                                                            \
    const int t = t2 + ((TE) / 64);                                            \
    RD_A(0, 0, BUF) RD_B(0, BUF)                                               \
    if (t + 1 < NT) { SG_B((BUF) ^ 1, 1, (TE) + 64) }                          \
    QUAD(0, 0, 0)                                                              \
    __builtin_amdgcn_s_barrier();                                              \
    RD_B(1, BUF)                                                               \
    if (t + 2 < NT) { SG_A(BUF, 0, (TE) + 128) }                               \
    QUAD(0, 0, 1)                                                              \
    __builtin_amdgcn_s_barrier();                                              \
    RD_A(0, 1, BUF)                                                            \
    if (t + 2 < NT) { SG_B(BUF, 0, (TE) + 128) }                               \
    QUAD(0, 1, 0)                                                              \
    __builtin_amdgcn_s_barrier();                                              \
    if (t + 2 < NT) { SG_A(BUF, 1, (TE) + 128) }                               \
    QUAD(0, 1, 1)                                                              \
    if (t + 2 < NT) { VM_PRO(); }                                              \
    else            { asm volatile("s_waitcnt vmcnt(0)" ::: "memory"); }       \
    __builtin_amdgcn_s_barrier();                                              \
  }

// r11 pipelined tile (for 128^2): Gray order (0,0),(0,1),(1,1),(1,0)
#define TILE_P(BUF, TE)                                                        \
  {                                                                            \
    const int t = t2 + ((TE) / 64);                                            \
    if (t + 1 < NT) { SG_B((BUF) ^ 1, 1, (TE) + 64) }                          \
    LGK0()                                                                     \
    RD_B(1, BUF)                                                               \
    QUAD(0, 0, 0)                                                              \
    __builtin_amdgcn_s_barrier();                                              \
    if (t + 2 < NT) { SG_A(BUF, 0, (TE) + 128) }                               \
    LGK0()                                                                     \
    RD_A(1, 1, BUF)                                                            \
    QUAD(0, 0, 1)                                                              \
    __builtin_amdgcn_s_barrier();                                              \
    if (t + 2 < NT) { SG_B(BUF, 0, (TE) + 128) }                               \
    LGK0()                                                                     \
    QUAD(1, 1, 1)                                                              \
    if (t + 2 < NT) { asm volatile("s_waitcnt vmcnt(2)" ::: "memory"); }       \
    else            { asm volatile("s_waitcnt vmcnt(0)" ::: "memory"); }       \
    __builtin_amdgcn_s_barrier();                                              \
    __builtin_amdgcn_sched_barrier(0);                                         \
    if (t + 1 < NT) { RD_A(0, 0, (BUF) ^ 1) }                                  \
    QUAD(1, 1, 0)                                                              \
    if (t + 1 < NT) { RD_B(0, (BUF) ^ 1) }                                     \
    if (t + 2 < NT) { SG_A(BUF, 1, (TE) + 128) }                               \
    __builtin_amdgcn_s_barrier();                                              \
  }

template<int BM, int BN, int EPI, int SWAP, int MINW, int PIPE>
__global__ __launch_bounds__(512, MINW)
void gemm8(const unsigned short* __restrict__ A, const unsigned short* __restrict__ Bw,
           const float* __restrict__ bias0, const float* __restrict__ bias1,
           const float* __restrict__ bias2, const void* __restrict__ res,
           void* __restrict__ C0, void* __restrict__ C1, void* __restrict__ C2,
           int M, int N, int K, float scale0, int nsplit, int vtL) {
  (void)M;
  constexpr int MI = BM / 32;
  constexpr int MH = MI / 2;
  constexpr int AHL = BM / 128;
  constexpr int NI = BN / 64;
  constexpr int NIH = NI / 2;
  constexpr int BHL = BN / 128;
  constexpr int AELEMS = BM * 64;
  constexpr int BELEMS = BN * 64;
  constexpr int ABYTES = AELEMS * 2;
  constexpr int BBYTES = BELEMS * 2;
  __shared__ unsigned short lds_all[2 * AELEMS + 2 * BELEMS];

  const int tid = threadIdx.x;
  const int w = tid >> 6, lane = tid & 63;
  const int wr = w >> 2, wcc = w & 3;
  const int ln = lane & 15, lg = lane >> 4;
  const int nbn = N / BN;
  const int bid = xcd_swz(blockIdx.x, gridDim.x);
  const int bm = bid / nbn, bn = bid % nbn;
  const int NT = K >> 6;

  const int crow = tid >> 3;
  const int cslot = (tid & 7) ^ (crow & 7);   // pre-swizzled global 16B slot

  const unsigned short* gA = A + ((size_t)(bm * BM) + crow) * K + cslot * 8;
  const unsigned short* gB = Bw + ((size_t)(bn * BN) + crow) * K + cslot * 8;

  bf16x8 af[PIPE ? 2 : 1][MH][2], bfr[NI][2];
  f32x4 acc[MI][NI] = {};

  // ---- prologue: tile0 fully, tile1 minus B1
  SG_A(0, 0, 0) SG_B(0, 0, 0) SG_B(0, 1, 0) SG_A(0, 1, 0)
  if (NT > 1) { SG_A(1, 0, 64) SG_B(1, 0, 64) SG_A(1, 1, 64) }
  VM_PRO();
  __builtin_amdgcn_s_barrier();
  if constexpr (PIPE) {
    __builtin_amdgcn_sched_barrier(0);
    RD_A(0, 0, 0) RD_B(0, 0)
  }

  for (int t2 = 0; t2 < NT; t2 += 2) {
    if constexpr (PIPE) { TILE_P(0, 0) TILE_P(1, 64) }
    else                { TILE_NP(0, 0) TILE_NP(1, 64) }
    gA += 128; gB += 128;
  }

  // ---- epilogue
  const int rowbase = bm * BM + wr * 16;
  const int colbase = bn * BN + wcc * 16;
  if constexpr (EPI == 1) {
    #pragma unroll
    for (int ni = 0; ni < NI; ++ni) {
      const int col = colbase + ni * 64 + ln;
      const float bv = bias0[col];
      const int hh = col >> 6, dd = col & 63;
      #pragma unroll
      for (int mi = 0; mi < MI; ++mi) {
        const int row0 = rowbase + mi * 32 + lg * 4;
        const int bb = row0 / vtL, ss = row0 % vtL;
        ushort4 pk;
        pk.x = f2bf(acc[mi][ni][0] + bv);
        pk.y = f2bf(acc[mi][ni][1] + bv);
        pk.z = f2bf(acc[mi][ni][2] + bv);
        pk.w = f2bf(acc[mi][ni][3] + bv);
        *(ushort4*)((unsigned short*)C0 + ((size_t)((bb * 16 + hh) * 64 + dd)) * vtL + ss) = pk;
      }
    }
  } else if constexpr (EPI == 4) {
    #pragma unroll
    for (int ni = 0; ni < NI; ++ni) {
      const int col = colbase + ni * 64 + ln;
      if (col < nsplit) {
        const float bv = bias0[col];
        #pragma unroll
        for (int mi = 0; mi < MI; ++mi) {
          const int row0 = rowbase + mi * 32 + lg * 4;
          #pragma unroll
          for (int r = 0; r < 4; ++r)
            ((unsigned short*)C0)[(size_t)(row0 + r) * nsplit + col] =
                f2bf(acc[mi][ni][r] + bv);
        }
      } else {
        const int vc = col - nsplit;
        const float bv = bias1[vc];
        const int hh = vc >> 6, dd = vc & 63;
        #pragma unroll
        for (int mi = 0; mi < MI; ++mi) {
          const int row0 = rowbase + mi * 32 + lg * 4;
          const int bb = row0 / vtL, ss = row0 % vtL;
          ushort4 pk;
          pk.x = f2bf(acc[mi][ni][0] + bv);
          pk.y = f2bf(acc[mi][ni][1] + bv);
          pk.z = f2bf(acc[mi][ni][2] + bv);
          pk.w = f2bf(acc[mi][ni][3] + bv);
          *(ushort4*)((unsigned short*)C1 + ((size_t)((bb * 16 + hh) * 64 + dd)) * vtL + ss) = pk;
        }
      }
    }
  } else if constexpr (EPI == 8) {
    // QKV fused (SWAP=1, segments of width nsplit=1024):
    // seg0: Q*scale -> C0 row-major; seg1: K -> C1 row-major;
    // seg2: V^T pack -> C2 [64bh][64][vtL] via 4 scalar stores (lane-consecutive ss)
    #pragma unroll
    for (int ni = 0; ni < NI; ++ni) {
      const int n0 = colbase + ni * 64 + lg * 4;
      const int seg = n0 / nsplit;            // uniform per ni per block
      const int nc = n0 - seg * nsplit;
      const float* bp = (seg == 0) ? bias0 : ((seg == 1) ? bias1 : bias2);
      const float4 b4 = *(const float4*)(bp + nc);
      #pragma unroll
      for (int mi = 0; mi < MI; ++mi) {
        const size_t mrow = (size_t)rowbase + mi * 32 + ln;
        float v0 = acc[mi][ni][0] + b4.x;
        float v1 = acc[mi][ni][1] + b4.y;
        float v2 = acc[mi][ni][2] + b4.z;
        float v3 = acc[mi][ni][3] + b4.w;
        if (seg == 0) {
          ushort4 pk;
          pk.x = f2bf(v0 * scale0); pk.y = f2bf(v1 * scale0);
          pk.z = f2bf(v2 * scale0); pk.w = f2bf(v3 * scale0);
          *(ushort4*)((unsigned short*)C0 + mrow * nsplit + nc) = pk;
        } else if (seg == 1) {
          ushort4 pk;
          pk.x = f2bf(v0); pk.y = f2bf(v1); pk.z = f2bf(v2); pk.w = f2bf(v3);
          *(ushort4*)((unsigned short*)C1 + mrow * nsplit + nc) = pk;
        } else {
          const int bb = (int)(mrow / vtL), ss = (int)(mrow % vtL);
          const int hh = nc >> 6, dd = nc & 63;
          unsigned short* vt = (unsigned short*)C2 +
              ((size_t)((bb * 16 + hh) * 64 + dd)) * vtL + ss;
          vt[0 * (size_t)vtL] = f2bf(v0);
          vt[1 * (size_t)vtL] = f2bf(v1);
          vt[2 * (size_t)vtL] = f2bf(v2);
          vt[3 * (size_t)vtL] = f2bf(v3);
        }
      }
    }
  } else {
    #pragma unroll
    for (int ni = 0; ni < NI; ++ni) {
      const int n0 = colbase + ni * 64 + lg * 4;
      const bool lo = (n0 < nsplit);
      const float* bp = lo ? bias0 : bias1;
      const float sc = lo ? scale0 : 1.0f;
      const int nc = lo ? n0 : n0 - nsplit;
      const int ldc = lo ? nsplit : N - nsplit;
      void* Cp = lo ? C0 : C1;
      const float4 b4 = *(const float4*)(bp + nc);
      #pragma unroll
      for (int mi = 0; mi < MI; ++mi) {
        const size_t mrow = (size_t)rowbase + mi * 32 + ln;
        float v0 = acc[mi][ni][0] + b4.x;
        float v1 = acc[mi][ni][1] + b4.y;
        float v2 = acc[mi][ni][2] + b4.z;
        float v3 = acc[mi][ni][3] + b4.w;
        if constexpr (EPI == 0) {
          ushort4 pk;
          pk.x = f2bf(v0 * sc); pk.y = f2bf(v1 * sc);
          pk.z = f2bf(v2 * sc); pk.w = f2bf(v3 * sc);
          *(ushort4*)((unsigned short*)Cp + mrow * ldc + nc) = pk;
        } else if constexpr (EPI == 5) {
          const float4 r4 = *(const float4*)((const float*)res + mrow * ldc + nc);
          ushort4 pk;
          pk.x = f2bf(v0 + r4.x); pk.y = f2bf(v1 + r4.y);
          pk.z = f2bf(v2 + r4.z); pk.w = f2bf(v3 + r4.w);
          *(ushort4*)((unsigned short*)Cp + mrow * ldc + nc) = pk;
        } else if constexpr (EPI == 6) {
          const ushort4 rb = *(const ushort4*)((const unsigned short*)res + mrow * ldc + nc);
          ushort4 pk;
          pk.x = f2bf(v0 + bf2f(rb.x)); pk.y = f2bf(v1 + bf2f(rb.y));
          pk.z = f2bf(v2 + bf2f(rb.z)); pk.w = f2bf(v3 + bf2f(rb.w));
          *(ushort4*)((unsigned short*)Cp + mrow * ldc + nc) = pk;
        } else if constexpr (EPI == 7) {
          const ushort4 rb = *(const ushort4*)((const unsigned short*)res + mrow * ldc + nc);
          float4 o4 = { v0 + bf2f(rb.x), v1 + bf2f(rb.y),
                        v2 + bf2f(rb.z), v3 + bf2f(rb.w) };
          *(float4*)((float*)Cp + mrow * ldc + nc) = o4;
        } else {
          ushort4 pk;
          pk.x = f2bf(gelu_fast(v0)); pk.y = f2bf(gelu_fast(v1));
          pk.z = f2bf(gelu_fast(v2)); pk.w = f2bf(gelu_fast(v3));
          *(ushort4*)((unsigned short*)Cp + mrow * ldc + nc) = pk;
        }
      }
    }
  }
}

// ---------------------------------------------------------------- flash attention, 2 q-tiles/wave (r15)
__global__ __launch_bounds__(256, 2)
void flash_k(const unsigned short* __restrict__ Q, const unsigned short* __restrict__ Kg,
             const unsigned short* __restrict__ VT, unsigned short* __restrict__ O,
             int Lq, int Lkpad, int kvlen) {
  const int qblocks = Lq >> 8;
  const int bid = xcd_swz(blockIdx.x, gridDim.x);
  const int bh = bid / qblocks, qb = bid - bh * qblocks;
  const int b = bh >> 4, h = bh & 15;
  const int tid = threadIdx.x, w = tid >> 6, lane = tid & 63;
  const int l31 = lane & 31, hi = lane >> 5;

  __shared__ unsigned short Ks[2][64 * 64];
  __shared__ unsigned short Vs[2][64 * 64];

  const size_t qrow0 = (size_t)b * Lq + qb * 256 + w * 64 + l31;  // +u*32
  bf16x8 qf[2][4];
  #pragma unroll
  for (int u = 0; u < 2; ++u)
    #pragma unroll
    for (int ds = 0; ds < 4; ++ds)
      qf[u][ds] = *(const bf16x8*)(Q + (qrow0 + u * 32) * 1024 + h * 64 + ds * 16 + hi * 8);

  f32x16 oacc[2][2] = {};
  f32x4 lacc[2] = {};

  const int nst = (kvlen + 63) >> 6;
  const int srow = lane >> 3;
  const int gslot = (lane & 7) ^ srow;

  auto STAGE = [&](int buf, int st) {
    #pragma unroll
    for (int i = 0; i < 2; ++i) {
      const int r = i * 32 + w * 8 + srow;
      gload16(Kg + ((size_t)b * Lkpad + st * 64 + r) * 1024 + h * 64 + gslot * 8,
              &Ks[buf][(i * 32 + w * 8) * 64]);
      gload16(VT + ((size_t)bh * 64 + r) * Lkpad + (size_t)st * 64 + gslot * 8,
              &Vs[buf][(i * 32 + w * 8) * 64]);
    }
  };

  STAGE(0, 0);

  for (int st = 0; st < nst; ++st) {
    const int cur = st & 1;
    __syncthreads();
    if (st + 1 < nst) STAGE(cur ^ 1, st + 1);

    const char* Kb = (const char*)Ks[cur];
    const char* Vb = (const char*)Vs[cur];

    #pragma unroll
    for (int kb = 0; kb < 2; ++kb) {
      f32x16 s[2] = {};
      {
        const int r = kb * 32 + l31;
        const int sw = (r & 7) << 4;
        __builtin_amdgcn_s_setprio(1);
        #pragma unroll
        for (int ds = 0; ds < 4; ++ds) {
          bf16x8 kf = *(const bf16x8*)(Kb + r * 128 + ((ds * 32 + hi * 16) ^ sw));
          s[0] = __builtin_amdgcn_mfma_f32_32x32x16_bf16(kf, qf[0][ds], s[0], 0, 0, 0);
          s[1] = __builtin_amdgcn_mfma_f32_32x32x16_bf16(kf, qf[1][ds], s[1], 0, 0, 0);
        }
        __builtin_amdgcn_s_setprio(0);
      }

      if (st * 64 + 64 > kvlen) {
        const int kbase = st * 64 + kb * 32 + hi * 4;
        #pragma unroll
        for (int u = 0; u < 2; ++u)
          #pragma unroll
          for (int r = 0; r < 16; ++r)
            if (kbase + (r & 3) + 8 * (r >> 2) >= kvlen) s[u][r] = -1e30f;
      }

      bf16x8 pf[2][2];
      #pragma unroll
      for (int u = 0; u < 2; ++u) {
        #pragma unroll
        for (int r = 0; r < 16; ++r) s[u][r] = __builtin_amdgcn_exp2f(s[u][r]);
        #pragma unroll
        for (int rq = 0; rq < 4; ++rq) {
          f32x4 t = { s[u][rq * 4 + 0], s[u][rq * 4 + 1], s[u][rq * 4 + 2], s[u][rq * 4 + 3] };
          lacc[u] += t;
        }
        #pragma unroll
        for (int m = 0; m < 2; ++m) {
          unsigned u0 = cvtpk(s[u][8 * m + 0], s[u][8 * m + 1]);
          unsigned u1 = cvtpk(s[u][8 * m + 2], s[u][8 * m + 3]);
          unsigned u2 = cvtpk(s[u][8 * m + 4], s[u][8 * m + 5]);
          unsigned u3 = cvtpk(s[u][8 * m + 6], s[u][8 * m + 7]);
          asm volatile("v_permlane32_swap_b32 %0, %1" : "+v"(u0), "+v"(u2));
          asm volatile("v_permlane32_swap_b32 %0, %1" : "+v"(u1), "+v"(u3));
          union { unsigned uu[4]; bf16x8 v; } fr;
          fr.uu[0] = u0; fr.uu[1] = u1; fr.uu[2] = u2; fr.uu[3] = u3;
          pf[u][m] = fr.v;
        }
      }

      {
        const int sw2 = (l31 & 7) << 4;
        __builtin_amdgcn_s_setprio(1);
        #pragma unroll
        for (int db = 0; db < 2; ++db) {
          const int r = db * 32 + l31;
          #pragma unroll
          for (int m = 0; m < 2; ++m) {
            bf16x8 vf = *(const bf16x8*)(Vb + r * 128 +
                          ((kb * 64 + m * 32 + hi * 16) ^ sw2));
            oacc[0][db] = __builtin_amdgcn_mfma_f32_32x32x16_bf16(vf, pf[0][m], oacc[0][db], 0, 0, 0);
            oacc[1][db] = __builtin_amdgcn_mfma_f32_32x32x16_bf16(vf, pf[1][m], oacc[1][db], 0, 0, 0);
          }
        }
        __builtin_amdgcn_s_setprio(0);
      }
    }
  }

  #pragma unroll
  for (int u = 0; u < 2; ++u) {
    float lt = lacc[u][0] + lacc[u][1] + lacc[u][2] + lacc[u][3];
    lt += __shfl_xor(lt, 32);
    const float inv = 1.0f / lt;
    const size_t q = qrow0 + u * 32;
    #pragma unroll
    for (int db = 0; db < 2; ++db)
      #pragma unroll
      for (int rg = 0; rg < 4; ++rg) {
        ushort4 pk;
        pk.x = f2bf(oacc[u][db][rg * 4 + 0] * inv);
        pk.y = f2bf(oacc[u][db][rg * 4 + 1] * inv);
        pk.z = f2bf(oacc[u][db][rg * 4 + 2] * inv);
        pk.w = f2bf(oacc[u][db][rg * 4 + 3] * inv);
        *(ushort4*)(O + q * 1024 + h * 64 + db * 32 + rg * 8 + hi * 4) = pk;
      }
  }
}

// ---------------------------------------------------------------- host
extern "C" void kernel_launch(void* const* d_in, const int* in_sizes, int n_in,
                              void* d_out, int out_size, void* d_ws, size_t ws_size,
                              hipStream_t stream) {
  (void)in_sizes; (void)n_in; (void)out_size; (void)ws_size;
  const float* x     = (const float*)d_in[0];
  const float* ctx   = (const float*)d_in[1];
  const float* ln1_w = (const float*)d_in[2];
  const float* ln1_b = (const float*)d_in[3];
  const float* ln2_w = (const float*)d_in[4];
  const float* ln2_b = (const float*)d_in[5];
  const float* ln3_w = (const float*)d_in[6];
  const float* ln3_b = (const float*)d_in[7];
  const float* sa_qw = (const float*)d_in[8];  const float* sa_qb = (const float*)d_in[9];
  const float* sa_kw = (const float*)d_in[10]; const float* sa_kb = (const float*)d_in[11];
  const float* sa_vw = (const float*)d_in[12]; const float* sa_vb = (const float*)d_in[13];
  const float* sa_pw = (const float*)d_in[14]; const float* sa_pb = (const float*)d_in[15];
  const float* ca_qw = (const float*)d_in[16]; const float* ca_qb = (const float*)d_in[17];
  const float* ca_kw = (const float*)d_in[18]; const float* ca_kb = (const float*)d_in[19];
  const float* ca_vw = (const float*)d_in[20]; const float* ca_vb = (const float*)d_in[21];
  const float* ca_pw = (const float*)d_in[22]; const float* ca_pb = (const float*)d_in[23];
  const float* fc1_w = (const float*)d_in[24]; const float* fc1_b = (const float*)d_in[25];
  const float* fc2_w = (const float*)d_in[26]; const float* fc2_b = (const float*)d_in[27];

  char* ws = (char*)d_ws;
  size_t o = 0;
  auto give = [&](size_t bytes) { size_t r = o; o += (bytes + 255) & ~(size_t)255; return r; };
  const size_t SQ = 1048576, SC = 786432, SF = 4194304;
  unsigned short* w_qkv = (unsigned short*)(ws + give(3 * SQ * 2));  // [3072][1024] Q,K,V
  unsigned short* w_p   = (unsigned short*)(ws + give(SQ * 2));
  unsigned short* w_caq = (unsigned short*)(ws + give(SQ * 2));
  unsigned short* w_cakv= (unsigned short*)(ws + give(2 * SC * 2)); // [2048][768] (K then V)
  unsigned short* w_cap = (unsigned short*)(ws + give(SQ * 2));
  unsigned short* w_f1  = (unsigned short*)(ws + give(SF * 2));
  unsigned short* w_f2  = (unsigned short*)(ws + give(SF * 2));
  unsigned short* ctxb  = (unsigned short*)(ws + give(512 * 768 * 2));
  unsigned short* hbuf  = (unsigned short*)(ws + give(8192 * 1024 * 2));
  unsigned short* qbuf  = (unsigned short*)(ws + give(8192 * 1024 * 2));
  unsigned short* kbuf  = (unsigned short*)(ws + give(8192 * 1024 * 2));
  unsigned short* vtbuf = (unsigned short*)(ws + give(8192 * 1024 * 2));
  unsigned short* obuf  = (unsigned short*)(ws + give(8192 * 1024 * 2));
  unsigned short* xcb   = (unsigned short*)(ws + give(8192 * 1024 * 2));  // bf16 residual stream
  unsigned short* gbuf  = qbuf;  // aliases qbuf..obuf (exactly 64 MiB contiguous)

  const float QSCALE = 0.125f * 1.44269504088896341f;  // SCALE * log2(e)

  WJobs jb;
  jb.j[0] = { sa_qw, w_qkv,           (int)(SQ / 1024) };
  jb.j[1] = { sa_kw, w_qkv + SQ,      (int)(SQ / 1024) };
  jb.j[2] = { sa_vw, w_qkv + 2 * SQ,  (int)(SQ / 1024) };
  jb.j[3] = { sa_pw, w_p,             (int)(SQ / 1024) };
  jb.j[4] = { ca_qw, w_caq,           (int)(SQ / 1024) };
  jb.j[5] = { ca_kw, w_cakv,          (int)(SC / 1024) };
  jb.j[6] = { ca_vw, w_cakv + SC,     (int)(SC / 1024) };
  jb.j[7] = { ca_pw, w_cap,           (int)(SQ / 1024) };
  jb.j[8] = { fc1_w, w_f1,            (int)(SF / 1024) };
  jb.j[9] = { fc2_w, w_f2,            (int)(SF / 1024) };
  int totblk = 0;
  for (int k = 0; k < 10; ++k) totblk += jb.j[k].nblk;

  wconv_k<<<totblk, 256, 0, stream>>>(jb);
  ctxpad_k<<<384, 256, 0, stream>>>(ctx, ctxb);

  // ---- self attention (Q,K,V fused: N=3072, grid 32*12=384)
  ln_k<0><<<8192, 256, 0, stream>>>(x, ln1_w, ln1_b, hbuf);
  gemm8<256, 256, 8, 1, 2, 0><<<384, 512, 0, stream>>>(hbuf, w_qkv, sa_qb, sa_kb, sa_vb, nullptr,
                                                       qbuf, kbuf, vtbuf,
                                                       8192, 3072, 1024, QSCALE, 1024, 2048);
  flash_k<<<512, 256, 0, stream>>>(qbuf, kbuf, vtbuf, obuf, 2048, 2048, 2048);
  gemm8<128, 128, 5, 1, 4, 1><<<512, 512, 0, stream>>>(obuf, w_p, sa_pb, nullptr, nullptr, x, xcb, nullptr, nullptr,
                                                       8192, 1024, 1024, 1.0f, 1024, 0);

  // ---- cross attention
  ln_k<1><<<8192, 256, 0, stream>>>(xcb, ln2_w, ln2_b, hbuf);
  gemm8<128, 128, 0, 1, 4, 1><<<512, 512, 0, stream>>>(hbuf, w_caq, ca_qb, nullptr, nullptr, nullptr, qbuf, nullptr, nullptr,
                                                       8192, 1024, 1024, QSCALE, 1024, 0);
  gemm8<128, 128, 4, 0, 4, 1><<<64, 512, 0, stream>>>(ctxb, w_cakv, ca_kb, ca_vb, nullptr, nullptr, kbuf, vtbuf, nullptr,
                                                      512, 2048, 768, 1.0f, 1024, 128);
  flash_k<<<512, 256, 0, stream>>>(qbuf, kbuf, vtbuf, obuf, 2048, 128, 77);
  gemm8<128, 128, 6, 1, 4, 1><<<512, 512, 0, stream>>>(obuf, w_cap, ca_pb, nullptr, nullptr, xcb, xcb, nullptr, nullptr,
                                                       8192, 1024, 1024, 1.0f, 1024, 0);

  // ---- FFN
  ln_k<1><<<8192, 256, 0, stream>>>(xcb, ln3_w, ln3_b, hbuf);
  gemm8<256, 256, 3, 1, 2, 0><<<512, 512, 0, stream>>>(hbuf, w_f1, fc1_b, nullptr, nullptr, nullptr, gbuf, nullptr, nullptr,
                                                       8192, 4096, 1024, 1.0f, 4096, 0);
  gemm8<128, 128, 7, 1, 4, 1><<<512, 512, 0, stream>>>(gbuf, w_f2, fc2_b, nullptr, nullptr, xcb, d_out, nullptr, nullptr,
                                                       8192, 1024, 4096, 1.0f, 1024, 0);
}

// Round 21
// 444.236 us; speedup vs baseline: 1.0293x; 1.0293x over previous
//
#include <hip/hip_runtime.h>
#include <hip/hip_bf16.h>
#include <cstdint>
#include <cstddef>

typedef __attribute__((ext_vector_type(8))) short bf16x8;
typedef __attribute__((ext_vector_type(4))) float f32x4;
typedef __attribute__((ext_vector_type(16))) float f32x16;

__device__ __forceinline__ unsigned short f2bf(float f) {
  union { float f; unsigned u; } c; c.f = f;
  unsigned r = c.u + 0x7FFFu + ((c.u >> 16) & 1u);
  return (unsigned short)(r >> 16);
}

__device__ __forceinline__ float bf2f(unsigned short u) {
  union { unsigned u; float f; } c; c.u = ((unsigned)u) << 16;
  return c.f;
}

__device__ __forceinline__ unsigned cvtpk(float lo, float hi) {
  unsigned r;
  asm("v_cvt_pk_bf16_f32 %0, %1, %2" : "=v"(r) : "v"(lo), "v"(hi));
  return r;
}

__device__ __forceinline__ float gelu_fast(float v) {
  const float u = v * (0.7978845608f + 0.0356774081f * v * v);
  const float a = fminf(-2.8853900818f * u, 80.0f);
  return v / (1.0f + exp2f(a));
}

__device__ __forceinline__ int xcd_swz(int bid, int nwg) {
  const int cpx = nwg >> 3;  // all grids here are %8==0
  return (bid & 7) * cpx + (bid >> 3);
}

typedef const __attribute__((address_space(1))) unsigned int* gas_ptr;
typedef __attribute__((address_space(3))) unsigned int* las_ptr;

__device__ __forceinline__ void gload16(const unsigned short* g, unsigned short* l) {
  __builtin_amdgcn_global_load_lds((gas_ptr)g, (las_ptr)l, 16, 0, 0);
}

// ---------------------------------------------------------------- fused weight convert
struct WJ { const float* s; unsigned short* d; int nblk; };
struct WJobs { WJ j[10]; };

__global__ void wconv_k(WJobs jb) {
  const int bid = blockIdx.x;
  int base = 0, ji = -1;
  #pragma unroll
  for (int k = 0; k < 10; ++k) {
    const int nb = jb.j[k].nblk;
    if (ji < 0) { if (bid < base + nb) ji = k; else base += nb; }
  }
  const int i = (bid - base) * 256 + threadIdx.x;
  float4 v = ((const float4*)jb.j[ji].s)[i];
  ushort4 o;
  o.x = f2bf(v.x); o.y = f2bf(v.y); o.z = f2bf(v.z); o.w = f2bf(v.w);
  ((ushort4*)jb.j[ji].d)[i] = o;
}

// context [4][77][768] fp32 -> padded [4][128][768] bf16 (pad rows = 0)
__global__ void ctxpad_k(const float* __restrict__ ctx, unsigned short* __restrict__ out) {
  int i = blockIdx.x * blockDim.x + threadIdx.x;
  if (i >= 512 * 192) return;
  int r = i / 192, c4 = i % 192;
  int b = r >> 7, s = r & 127;
  ushort4 o = {0, 0, 0, 0};
  if (s < 77) {
    float4 v = ((const float4*)(ctx + (size_t)(b * 77 + s) * 768))[c4];
    o.x = f2bf(v.x); o.y = f2bf(v.y); o.z = f2bf(v.z); o.w = f2bf(v.w);
  }
  ((ushort4*)out)[i] = o;
}

// ---------------------------------------------------------------- layernorm (INBF: 0=fp32 in, 1=bf16 in)
template<int INBF>
__global__ __launch_bounds__(256)
void ln_k(const void* __restrict__ xin, const float* __restrict__ w,
          const float* __restrict__ b, unsigned short* __restrict__ out) {
  int row = blockIdx.x, tid = threadIdx.x;
  float4 v;
  if constexpr (INBF) {
    ushort4 u = ((const ushort4*)((const unsigned short*)xin + (size_t)row * 1024))[tid];
    v.x = bf2f(u.x); v.y = bf2f(u.y); v.z = bf2f(u.z); v.w = bf2f(u.w);
  } else {
    v = ((const float4*)((const float*)xin + (size_t)row * 1024))[tid];
  }
  float s = v.x + v.y + v.z + v.w;
  float s2 = v.x * v.x + v.y * v.y + v.z * v.z + v.w * v.w;
  #pragma unroll
  for (int m = 1; m < 64; m <<= 1) { s += __shfl_xor(s, m); s2 += __shfl_xor(s2, m); }
  __shared__ float ps[4], ps2[4];
  int wv = tid >> 6;
  if ((tid & 63) == 0) { ps[wv] = s; ps2[wv] = s2; }
  __syncthreads();
  s = ps[0] + ps[1] + ps[2] + ps[3];
  s2 = ps2[0] + ps2[1] + ps2[2] + ps2[3];
  float mu = s * (1.0f / 1024.0f);
  float var = s2 * (1.0f / 1024.0f) - mu * mu;
  float rstd = rsqrtf(var + 1e-5f);
  float4 wv4 = ((const float4*)w)[tid];
  float4 bv4 = ((const float4*)b)[tid];
  ushort4 o;
  o.x = f2bf((v.x - mu) * rstd * wv4.x + bv4.x);
  o.y = f2bf((v.y - mu) * rstd * wv4.y + bv4.y);
  o.z = f2bf((v.z - mu) * rstd * wv4.z + bv4.z);
  o.w = f2bf((v.w - mu) * rstd * wv4.w + bv4.w);
  ((ushort4*)(out + (size_t)row * 1024))[tid] = o;
}

// ---------------------------------------------------------------- GEMM 8-phase
// PIPE=0: r13 structure (verified best for 256^2 / 1 block/CU).
// PIPE=1: r11 pipelined structure (128^2, 2 blocks/CU; fits 128-VGPR budget).
// EPI: 0=(acc+bias)*scale->bf16 (col-split C0/C1), 1=V^T pack (SWAP=0),
//      3=gelu->bf16, 4=col-split K/V (SWAP=0),
//      5=acc+bias+res(fp32)->bf16, 6=acc+bias+res(bf16)->bf16,
//      7=acc+bias+res(bf16)->fp32
#define SG_A(BUF, H, TE)                                                       \
  _Pragma("unroll")                                                            \
  for (int j = 0; j < AHL; ++j)                                                \
    __builtin_amdgcn_global_load_lds(                                          \
        (gas_ptr)(gA + (TE) + (size_t)((H) * (BM / 2) + j * 64) * (size_t)K),  \
        (las_ptr)(lds_all + (BUF) * AELEMS +                                   \
                  (((H) * (BM / 2) + j * 64) + w * 8) * 64),                   \
        16, 0, 0);

#define SG_B(BUF, H, TE)                                                       \
  _Pragma("unroll")                                                            \
  for (int j = 0; j < BHL; ++j)                                                \
    __builtin_amdgcn_global_load_lds(                                          \
        (gas_ptr)(gB + (TE) + (size_t)((H) * (BN / 2) + j * 64) * (size_t)K),  \
        (las_ptr)(lds_all + 2 * AELEMS + (BUF) * BELEMS +                      \
                  (((H) * (BN / 2) + j * 64) + w * 8) * 64),                   \
        16, 0, 0);

#define RD_A(D, MHh, BUF)                                                      \
  _Pragma("unroll")                                                            \
  for (int i = 0; i < MH; ++i) {                                               \
    const int r = ((MHh) * MH + i) * 32 + wr * 16 + ln;                        \
    _Pragma("unroll")                                                          \
    for (int kc = 0; kc < 2; ++kc)                                             \
      af[D][i][kc] = *(const bf16x8*)((const char*)lds_all + (BUF) * ABYTES +  \
                    r * 128 + (((kc * 4 + lg) ^ (r & 7)) * 16));               \
  }

#define RD_B(NHh, BUF)                                                         \
  _Pragma("unroll")                                                            \
  for (int i = 0; i < NIH; ++i) {                                              \
    const int ni = (NHh) * NIH + i;                                            \
    const int r = ni * 64 + wcc * 16 + ln;                                     \
    _Pragma("unroll")                                                          \
    for (int kc = 0; kc < 2; ++kc)                                             \
      bfr[ni][kc] = *(const bf16x8*)((const char*)lds_all + 2 * ABYTES +       \
                    (BUF) * BBYTES + r * 128 + (((kc * 4 + lg) ^ (r & 7)) * 16)); \
  }

#define QUAD(D, MHh, NHh)                                                      \
  __builtin_amdgcn_s_setprio(1);                                               \
  _Pragma("unroll")                                                            \
  for (int kc = 0; kc < 2; ++kc)                                               \
    _Pragma("unroll")                                                          \
    for (int i = 0; i < MH; ++i)                                               \
      _Pragma("unroll")                                                        \
      for (int j2 = 0; j2 < NIH; ++j2) {                                       \
        const int mi = (MHh) * MH + i, ni = (NHh) * NIH + j2;                  \
        if constexpr (SWAP)                                                    \
          acc[mi][ni] = __builtin_amdgcn_mfma_f32_16x16x32_bf16(               \
              bfr[ni][kc], af[D][i][kc], acc[mi][ni], 0, 0, 0);                \
        else                                                                   \
          acc[mi][ni] = __builtin_amdgcn_mfma_f32_16x16x32_bf16(               \
              af[D][i][kc], bfr[ni][kc], acc[mi][ni], 0, 0, 0);                \
      }                                                                        \
  __builtin_amdgcn_s_setprio(0);

#define VM_PRO()                                                               \
  do { if constexpr (BM == 256) asm volatile("s_waitcnt vmcnt(6)" ::: "memory"); \
       else                     asm volatile("s_waitcnt vmcnt(3)" ::: "memory"); } while (0)

#define LGK0()                                                                 \
  asm volatile("s_waitcnt lgkmcnt(0)" ::: "memory");                           \
  __builtin_amdgcn_sched_barrier(0);

// r13 non-pipelined tile (for 256^2)
#define TILE_NP(BUF, TE)                                                       \
  {                                                                            \
    const int t = t2 + ((TE) / 64);                                            \
    RD_A(0, 0, BUF) RD_B(0, BUF)                                               \
    if (t + 1 < NT) { SG_B((BUF) ^ 1, 1, (TE) + 64) }                          \
    QUAD(0, 0, 0)                                                              \
    __builtin_amdgcn_s_barrier();                                              \
    RD_B(1, BUF)                                                               \
    if (t + 2 < NT) { SG_A(BUF, 0, (TE) + 128) }                               \
    QUAD(0, 0, 1)                                                              \
    __builtin_amdgcn_s_barrier();                                              \
    RD_A(0, 1, BUF)                                                            \
    if (t + 2 < NT) { SG_B(BUF, 0, (TE) + 128) }                               \
    QUAD(0, 1, 0)                                                              \
    __builtin_amdgcn_s_barrier();                                              \
    if (t + 2 < NT) { SG_A(BUF, 1, (TE) + 128) }                               \
    QUAD(0, 1, 1)                                                              \
    if (t + 2 < NT) { VM_PRO(); }                                              \
    else            { asm volatile("s_waitcnt vmcnt(0)" ::: "memory"); }       \
    __builtin_amdgcn_s_barrier();                                              \
  }

// r11 pipelined tile (for 128^2): Gray order (0,0),(0,1),(1,1),(1,0)
#define TILE_P(BUF, TE)                                                        \
  {                                                                            \
    const int t = t2 + ((TE) / 64);                                            \
    if (t + 1 < NT) { SG_B((BUF) ^ 1, 1, (TE) + 64) }                          \
    LGK0()                                                                     \
    RD_B(1, BUF)                                                               \
    QUAD(0, 0, 0)                                                              \
    __builtin_amdgcn_s_barrier();                                              \
    if (t + 2 < NT) { SG_A(BUF, 0, (TE) + 128) }                               \
    LGK0()                                                                     \
    RD_A(1, 1, BUF)                                                            \
    QUAD(0, 0, 1)                                                              \
    __builtin_amdgcn_s_barrier();                                              \
    if (t + 2 < NT) { SG_B(BUF, 0, (TE) + 128) }                               \
    LGK0()                                                                     \
    QUAD(1, 1, 1)                                                              \
    if (t + 2 < NT) { asm volatile("s_waitcnt vmcnt(2)" ::: "memory"); }       \
    else            { asm volatile("s_waitcnt vmcnt(0)" ::: "memory"); }       \
    __builtin_amdgcn_s_barrier();                                              \
    __builtin_amdgcn_sched_barrier(0);                                         \
    if (t + 1 < NT) { RD_A(0, 0, (BUF) ^ 1) }                                  \
    QUAD(1, 1, 0)                                                              \
    if (t + 1 < NT) { RD_B(0, (BUF) ^ 1) }                                     \
    if (t + 2 < NT) { SG_A(BUF, 1, (TE) + 128) }                               \
    __builtin_amdgcn_s_barrier();                                              \
  }

template<int BM, int BN, int EPI, int SWAP, int MINW, int PIPE>
__global__ __launch_bounds__(512, MINW)
void gemm8(const unsigned short* __restrict__ A, const unsigned short* __restrict__ Bw,
           const float* __restrict__ bias0, const float* __restrict__ bias1,
           const void* __restrict__ res, void* __restrict__ C0, void* __restrict__ C1,
           int M, int N, int K, float scale0, int nsplit, int vtL) {
  (void)M;
  constexpr int MI = BM / 32;
  constexpr int MH = MI / 2;
  constexpr int AHL = BM / 128;
  constexpr int NI = BN / 64;
  constexpr int NIH = NI / 2;
  constexpr int BHL = BN / 128;
  constexpr int AELEMS = BM * 64;
  constexpr int BELEMS = BN * 64;
  constexpr int ABYTES = AELEMS * 2;
  constexpr int BBYTES = BELEMS * 2;
  __shared__ unsigned short lds_all[2 * AELEMS + 2 * BELEMS];

  const int tid = threadIdx.x;
  const int w = tid >> 6, lane = tid & 63;
  const int wr = w >> 2, wcc = w & 3;
  const int ln = lane & 15, lg = lane >> 4;
  const int nbn = N / BN;
  const int bid = xcd_swz(blockIdx.x, gridDim.x);
  const int bm = bid / nbn, bn = bid % nbn;
  const int NT = K >> 6;

  const int crow = tid >> 3;
  const int cslot = (tid & 7) ^ (crow & 7);   // pre-swizzled global 16B slot

  const unsigned short* gA = A + ((size_t)(bm * BM) + crow) * K + cslot * 8;
  const unsigned short* gB = Bw + ((size_t)(bn * BN) + crow) * K + cslot * 8;

  bf16x8 af[PIPE ? 2 : 1][MH][2], bfr[NI][2];
  f32x4 acc[MI][NI] = {};

  // ---- prologue: tile0 fully, tile1 minus B1
  SG_A(0, 0, 0) SG_B(0, 0, 0) SG_B(0, 1, 0) SG_A(0, 1, 0)
  if (NT > 1) { SG_A(1, 0, 64) SG_B(1, 0, 64) SG_A(1, 1, 64) }
  VM_PRO();
  __builtin_amdgcn_s_barrier();
  if constexpr (PIPE) {
    __builtin_amdgcn_sched_barrier(0);
    RD_A(0, 0, 0) RD_B(0, 0)
  }

  for (int t2 = 0; t2 < NT; t2 += 2) {
    if constexpr (PIPE) { TILE_P(0, 0) TILE_P(1, 64) }
    else                { TILE_NP(0, 0) TILE_NP(1, 64) }
    gA += 128; gB += 128;
  }

  // ---- epilogue
  const int rowbase = bm * BM + wr * 16;
  const int colbase = bn * BN + wcc * 16;
  if constexpr (EPI == 1) {
    #pragma unroll
    for (int ni = 0; ni < NI; ++ni) {
      const int col = colbase + ni * 64 + ln;
      const float bv = bias0[col];
      const int hh = col >> 6, dd = col & 63;
      #pragma unroll
      for (int mi = 0; mi < MI; ++mi) {
        const int row0 = rowbase + mi * 32 + lg * 4;
        const int bb = row0 / vtL, ss = row0 % vtL;
        ushort4 pk;
        pk.x = f2bf(acc[mi][ni][0] + bv);
        pk.y = f2bf(acc[mi][ni][1] + bv);
        pk.z = f2bf(acc[mi][ni][2] + bv);
        pk.w = f2bf(acc[mi][ni][3] + bv);
        *(ushort4*)((unsigned short*)C0 + ((size_t)((bb * 16 + hh) * 64 + dd)) * vtL + ss) = pk;
      }
    }
  } else if constexpr (EPI == 4) {
    #pragma unroll
    for (int ni = 0; ni < NI; ++ni) {
      const int col = colbase + ni * 64 + ln;
      if (col < nsplit) {
        const float bv = bias0[col];
        #pragma unroll
        for (int mi = 0; mi < MI; ++mi) {
          const int row0 = rowbase + mi * 32 + lg * 4;
          #pragma unroll
          for (int r = 0; r < 4; ++r)
            ((unsigned short*)C0)[(size_t)(row0 + r) * nsplit + col] =
                f2bf(acc[mi][ni][r] + bv);
        }
      } else {
        const int vc = col - nsplit;
        const float bv = bias1[vc];
        const int hh = vc >> 6, dd = vc & 63;
        #pragma unroll
        for (int mi = 0; mi < MI; ++mi) {
          const int row0 = rowbase + mi * 32 + lg * 4;
          const int bb = row0 / vtL, ss = row0 % vtL;
          ushort4 pk;
          pk.x = f2bf(acc[mi][ni][0] + bv);
          pk.y = f2bf(acc[mi][ni][1] + bv);
          pk.z = f2bf(acc[mi][ni][2] + bv);
          pk.w = f2bf(acc[mi][ni][3] + bv);
          *(ushort4*)((unsigned short*)C1 + ((size_t)((bb * 16 + hh) * 64 + dd)) * vtL + ss) = pk;
        }
      }
    }
  } else {
    #pragma unroll
    for (int ni = 0; ni < NI; ++ni) {
      const int n0 = colbase + ni * 64 + lg * 4;
      const bool lo = (n0 < nsplit);
      const float* bp = lo ? bias0 : bias1;
      const float sc = lo ? scale0 : 1.0f;
      const int nc = lo ? n0 : n0 - nsplit;
      const int ldc = lo ? nsplit : N - nsplit;
      void* Cp = lo ? C0 : C1;
      const float4 b4 = *(const float4*)(bp + nc);
      #pragma unroll
      for (int mi = 0; mi < MI; ++mi) {
        const size_t mrow = (size_t)rowbase + mi * 32 + ln;
        float v0 = acc[mi][ni][0] + b4.x;
        float v1 = acc[mi][ni][1] + b4.y;
        float v2 = acc[mi][ni][2] + b4.z;
        float v3 = acc[mi][ni][3] + b4.w;
        if constexpr (EPI == 0) {
          ushort4 pk;
          pk.x = f2bf(v0 * sc); pk.y = f2bf(v1 * sc);
          pk.z = f2bf(v2 * sc); pk.w = f2bf(v3 * sc);
          *(ushort4*)((unsigned short*)Cp + mrow * ldc + nc) = pk;
        } else if constexpr (EPI == 5) {
          // res fp32 -> out bf16
          const float4 r4 = *(const float4*)((const float*)res + mrow * ldc + nc);
          ushort4 pk;
          pk.x = f2bf(v0 + r4.x); pk.y = f2bf(v1 + r4.y);
          pk.z = f2bf(v2 + r4.z); pk.w = f2bf(v3 + r4.w);
          *(ushort4*)((unsigned short*)Cp + mrow * ldc + nc) = pk;
        } else if constexpr (EPI == 6) {
          // res bf16 -> out bf16 (in-place safe: same thread reads then writes)
          const ushort4 rb = *(const ushort4*)((const unsigned short*)res + mrow * ldc + nc);
          ushort4 pk;
          pk.x = f2bf(v0 + bf2f(rb.x)); pk.y = f2bf(v1 + bf2f(rb.y));
          pk.z = f2bf(v2 + bf2f(rb.z)); pk.w = f2bf(v3 + bf2f(rb.w));
          *(ushort4*)((unsigned short*)Cp + mrow * ldc + nc) = pk;
        } else if constexpr (EPI == 7) {
          // res bf16 -> out fp32
          const ushort4 rb = *(const ushort4*)((const unsigned short*)res + mrow * ldc + nc);
          float4 o4 = { v0 + bf2f(rb.x), v1 + bf2f(rb.y),
                        v2 + bf2f(rb.z), v3 + bf2f(rb.w) };
          *(float4*)((float*)Cp + mrow * ldc + nc) = o4;
        } else {
          ushort4 pk;
          pk.x = f2bf(gelu_fast(v0)); pk.y = f2bf(gelu_fast(v1));
          pk.z = f2bf(gelu_fast(v2)); pk.w = f2bf(gelu_fast(v3));
          *(ushort4*)((unsigned short*)Cp + mrow * ldc + nc) = pk;
        }
      }
    }
  }
}

// ---------------------------------------------------------------- flash attention, 2 q-tiles/wave (r15)
__global__ __launch_bounds__(256, 2)
void flash_k(const unsigned short* __restrict__ Q, const unsigned short* __restrict__ Kg,
             const unsigned short* __restrict__ VT, unsigned short* __restrict__ O,
             int Lq, int Lkpad, int kvlen) {
  const int qblocks = Lq >> 8;
  const int bid = xcd_swz(blockIdx.x, gridDim.x);
  const int bh = bid / qblocks, qb = bid - bh * qblocks;
  const int b = bh >> 4, h = bh & 15;
  const int tid = threadIdx.x, w = tid >> 6, lane = tid & 63;
  const int l31 = lane & 31, hi = lane >> 5;

  __shared__ unsigned short Ks[2][64 * 64];
  __shared__ unsigned short Vs[2][64 * 64];

  const size_t qrow0 = (size_t)b * Lq + qb * 256 + w * 64 + l31;  // +u*32
  bf16x8 qf[2][4];
  #pragma unroll
  for (int u = 0; u < 2; ++u)
    #pragma unroll
    for (int ds = 0; ds < 4; ++ds)
      qf[u][ds] = *(const bf16x8*)(Q + (qrow0 + u * 32) * 1024 + h * 64 + ds * 16 + hi * 8);

  f32x16 oacc[2][2] = {};
  f32x4 lacc[2] = {};

  const int nst = (kvlen + 63) >> 6;
  const int srow = lane >> 3;
  const int gslot = (lane & 7) ^ srow;

  auto STAGE = [&](int buf, int st) {
    #pragma unroll
    for (int i = 0; i < 2; ++i) {
      const int r = i * 32 + w * 8 + srow;
      gload16(Kg + ((size_t)b * Lkpad + st * 64 + r) * 1024 + h * 64 + gslot * 8,
              &Ks[buf][(i * 32 + w * 8) * 64]);
      gload16(VT + ((size_t)bh * 64 + r) * Lkpad + (size_t)st * 64 + gslot * 8,
              &Vs[buf][(i * 32 + w * 8) * 64]);
    }
  };

  STAGE(0, 0);

  for (int st = 0; st < nst; ++st) {
    const int cur = st & 1;
    __syncthreads();
    if (st + 1 < nst) STAGE(cur ^ 1, st + 1);

    const char* Kb = (const char*)Ks[cur];
    const char* Vb = (const char*)Vs[cur];

    #pragma unroll
    for (int kb = 0; kb < 2; ++kb) {
      f32x16 s[2] = {};
      {
        const int r = kb * 32 + l31;
        const int sw = (r & 7) << 4;
        __builtin_amdgcn_s_setprio(1);
        #pragma unroll
        for (int ds = 0; ds < 4; ++ds) {
          bf16x8 kf = *(const bf16x8*)(Kb + r * 128 + ((ds * 32 + hi * 16) ^ sw));
          s[0] = __builtin_amdgcn_mfma_f32_32x32x16_bf16(kf, qf[0][ds], s[0], 0, 0, 0);
          s[1] = __builtin_amdgcn_mfma_f32_32x32x16_bf16(kf, qf[1][ds], s[1], 0, 0, 0);
        }
        __builtin_amdgcn_s_setprio(0);
      }

      if (st * 64 + 64 > kvlen) {
        const int kbase = st * 64 + kb * 32 + hi * 4;
        #pragma unroll
        for (int u = 0; u < 2; ++u)
          #pragma unroll
          for (int r = 0; r < 16; ++r)
            if (kbase + (r & 3) + 8 * (r >> 2) >= kvlen) s[u][r] = -1e30f;
      }

      bf16x8 pf[2][2];
      #pragma unroll
      for (int u = 0; u < 2; ++u) {
        #pragma unroll
        for (int r = 0; r < 16; ++r) s[u][r] = __builtin_amdgcn_exp2f(s[u][r]);
        #pragma unroll
        for (int rq = 0; rq < 4; ++rq) {
          f32x4 t = { s[u][rq * 4 + 0], s[u][rq * 4 + 1], s[u][rq * 4 + 2], s[u][rq * 4 + 3] };
          lacc[u] += t;
        }
        #pragma unroll
        for (int m = 0; m < 2; ++m) {
          unsigned u0 = cvtpk(s[u][8 * m + 0], s[u][8 * m + 1]);
          unsigned u1 = cvtpk(s[u][8 * m + 2], s[u][8 * m + 3]);
          unsigned u2 = cvtpk(s[u][8 * m + 4], s[u][8 * m + 5]);
          unsigned u3 = cvtpk(s[u][8 * m + 6], s[u][8 * m + 7]);
          asm volatile("v_permlane32_swap_b32 %0, %1" : "+v"(u0), "+v"(u2));
          asm volatile("v_permlane32_swap_b32 %0, %1" : "+v"(u1), "+v"(u3));
          union { unsigned uu[4]; bf16x8 v; } fr;
          fr.uu[0] = u0; fr.uu[1] = u1; fr.uu[2] = u2; fr.uu[3] = u3;
          pf[u][m] = fr.v;
        }
      }

      {
        const int sw2 = (l31 & 7) << 4;
        __builtin_amdgcn_s_setprio(1);
        #pragma unroll
        for (int db = 0; db < 2; ++db) {
          const int r = db * 32 + l31;
          #pragma unroll
          for (int m = 0; m < 2; ++m) {
            bf16x8 vf = *(const bf16x8*)(Vb + r * 128 +
                          ((kb * 64 + m * 32 + hi * 16) ^ sw2));
            oacc[0][db] = __builtin_amdgcn_mfma_f32_32x32x16_bf16(vf, pf[0][m], oacc[0][db], 0, 0, 0);
            oacc[1][db] = __builtin_amdgcn_mfma_f32_32x32x16_bf16(vf, pf[1][m], oacc[1][db], 0, 0, 0);
          }
        }
        __builtin_amdgcn_s_setprio(0);
      }
    }
  }

  #pragma unroll
  for (int u = 0; u < 2; ++u) {
    float lt = lacc[u][0] + lacc[u][1] + lacc[u][2] + lacc[u][3];
    lt += __shfl_xor(lt, 32);
    const float inv = 1.0f / lt;
    const size_t q = qrow0 + u * 32;
    #pragma unroll
    for (int db = 0; db < 2; ++db)
      #pragma unroll
      for (int rg = 0; rg < 4; ++rg) {
        ushort4 pk;
        pk.x = f2bf(oacc[u][db][rg * 4 + 0] * inv);
        pk.y = f2bf(oacc[u][db][rg * 4 + 1] * inv);
        pk.z = f2bf(oacc[u][db][rg * 4 + 2] * inv);
        pk.w = f2bf(oacc[u][db][rg * 4 + 3] * inv);
        *(ushort4*)(O + q * 1024 + h * 64 + db * 32 + rg * 8 + hi * 4) = pk;
      }
  }
}

// ---------------------------------------------------------------- host
extern "C" void kernel_launch(void* const* d_in, const int* in_sizes, int n_in,
                              void* d_out, int out_size, void* d_ws, size_t ws_size,
                              hipStream_t stream) {
  (void)in_sizes; (void)n_in; (void)out_size; (void)ws_size;
  const float* x     = (const float*)d_in[0];
  const float* ctx   = (const float*)d_in[1];
  const float* ln1_w = (const float*)d_in[2];
  const float* ln1_b = (const float*)d_in[3];
  const float* ln2_w = (const float*)d_in[4];
  const float* ln2_b = (const float*)d_in[5];
  const float* ln3_w = (const float*)d_in[6];
  const float* ln3_b = (const float*)d_in[7];
  const float* sa_qw = (const float*)d_in[8];  const float* sa_qb = (const float*)d_in[9];
  const float* sa_kw = (const float*)d_in[10]; const float* sa_kb = (const float*)d_in[11];
  const float* sa_vw = (const float*)d_in[12]; const float* sa_vb = (const float*)d_in[13];
  const float* sa_pw = (const float*)d_in[14]; const float* sa_pb = (const float*)d_in[15];
  const float* ca_qw = (const float*)d_in[16]; const float* ca_qb = (const float*)d_in[17];
  const float* ca_kw = (const float*)d_in[18]; const float* ca_kb = (const float*)d_in[19];
  const float* ca_vw = (const float*)d_in[20]; const float* ca_vb = (const float*)d_in[21];
  const float* ca_pw = (const float*)d_in[22]; const float* ca_pb = (const float*)d_in[23];
  const float* fc1_w = (const float*)d_in[24]; const float* fc1_b = (const float*)d_in[25];
  const float* fc2_w = (const float*)d_in[26]; const float* fc2_b = (const float*)d_in[27];

  char* ws = (char*)d_ws;
  size_t o = 0;
  auto give = [&](size_t bytes) { size_t r = o; o += (bytes + 255) & ~(size_t)255; return r; };
  const size_t SQ = 1048576, SC = 786432, SF = 4194304;
  unsigned short* w_qk  = (unsigned short*)(ws + give(2 * SQ * 2));  // [2048][1024]
  unsigned short* w_v   = (unsigned short*)(ws + give(SQ * 2));
  unsigned short* w_p   = (unsigned short*)(ws + give(SQ * 2));
  unsigned short* w_caq = (unsigned short*)(ws + give(SQ * 2));
  unsigned short* w_cakv= (unsigned short*)(ws + give(2 * SC * 2)); // [2048][768] (K then V)
  unsigned short* w_cap = (unsigned short*)(ws + give(SQ * 2));
  unsigned short* w_f1  = (unsigned short*)(ws + give(SF * 2));
  unsigned short* w_f2  = (unsigned short*)(ws + give(SF * 2));
  unsigned short* ctxb  = (unsigned short*)(ws + give(512 * 768 * 2));
  unsigned short* hbuf  = (unsigned short*)(ws + give(8192 * 1024 * 2));
  unsigned short* qbuf  = (unsigned short*)(ws + give(8192 * 1024 * 2));
  unsigned short* kbuf  = (unsigned short*)(ws + give(8192 * 1024 * 2));
  unsigned short* vtbuf = (unsigned short*)(ws + give(8192 * 1024 * 2));
  unsigned short* obuf  = (unsigned short*)(ws + give(8192 * 1024 * 2));
  unsigned short* xcb   = (unsigned short*)(ws + give(8192 * 1024 * 2));  // bf16 residual stream
  unsigned short* gbuf  = qbuf;  // aliases qbuf..obuf (exactly 64 MiB contiguous)

  const float QSCALE = 0.125f * 1.44269504088896341f;  // SCALE * log2(e)

  WJobs jb;
  jb.j[0] = { sa_qw, w_qk,           (int)(SQ / 1024) };
  jb.j[1] = { sa_kw, w_qk + SQ,      (int)(SQ / 1024) };
  jb.j[2] = { sa_vw, w_v,            (int)(SQ / 1024) };
  jb.j[3] = { sa_pw, w_p,            (int)(SQ / 1024) };
  jb.j[4] = { ca_qw, w_caq,          (int)(SQ / 1024) };
  jb.j[5] = { ca_kw, w_cakv,         (int)(SC / 1024) };
  jb.j[6] = { ca_vw, w_cakv + SC,    (int)(SC / 1024) };
  jb.j[7] = { ca_pw, w_cap,          (int)(SQ / 1024) };
  jb.j[8] = { fc1_w, w_f1,           (int)(SF / 1024) };
  jb.j[9] = { fc2_w, w_f2,           (int)(SF / 1024) };
  int totblk = 0;
  for (int k = 0; k < 10; ++k) totblk += jb.j[k].nblk;

  wconv_k<<<totblk, 256, 0, stream>>>(jb);
  ctxpad_k<<<384, 256, 0, stream>>>(ctx, ctxb);

  // ---- self attention
  ln_k<0><<<8192, 256, 0, stream>>>(x, ln1_w, ln1_b, hbuf);
  gemm8<256, 256, 0, 1, 2, 0><<<256, 512, 0, stream>>>(hbuf, w_qk, sa_qb, sa_kb, nullptr, qbuf, kbuf,
                                                       8192, 2048, 1024, QSCALE, 1024, 0);
  gemm8<128, 128, 1, 0, 4, 1><<<512, 512, 0, stream>>>(hbuf, w_v, sa_vb, nullptr, nullptr, vtbuf, nullptr,
                                                       8192, 1024, 1024, 1.0f, 1024, 2048);
  flash_k<<<512, 256, 0, stream>>>(qbuf, kbuf, vtbuf, obuf, 2048, 2048, 2048);
  gemm8<128, 128, 5, 1, 4, 1><<<512, 512, 0, stream>>>(obuf, w_p, sa_pb, nullptr, x, xcb, nullptr,
                                                       8192, 1024, 1024, 1.0f, 1024, 0);

  // ---- cross attention
  ln_k<1><<<8192, 256, 0, stream>>>(xcb, ln2_w, ln2_b, hbuf);
  gemm8<128, 128, 0, 1, 4, 1><<<512, 512, 0, stream>>>(hbuf, w_caq, ca_qb, nullptr, nullptr, qbuf, nullptr,
                                                       8192, 1024, 1024, QSCALE, 1024, 0);
  gemm8<128, 128, 4, 0, 4, 1><<<64, 512, 0, stream>>>(ctxb, w_cakv, ca_kb, ca_vb, nullptr, kbuf, vtbuf,
                                                      512, 2048, 768, 1.0f, 1024, 128);
  flash_k<<<512, 256, 0, stream>>>(qbuf, kbuf, vtbuf, obuf, 2048, 128, 77);
  gemm8<128, 128, 6, 1, 4, 1><<<512, 512, 0, stream>>>(obuf, w_cap, ca_pb, nullptr, xcb, xcb, nullptr,
                                                       8192, 1024, 1024, 1.0f, 1024, 0);

  // ---- FFN
  ln_k<1><<<8192, 256, 0, stream>>>(xcb, ln3_w, ln3_b, hbuf);
  gemm8<256, 256, 3, 1, 2, 0><<<512, 512, 0, stream>>>(hbuf, w_f1, fc1_b, nullptr, nullptr, gbuf, nullptr,
                                                       8192, 4096, 1024, 1.0f, 4096, 0);
  gemm8<128, 128, 7, 1, 4, 1><<<512, 512, 0, stream>>>(gbuf, w_f2, fc2_b, nullptr, xcb, d_out, nullptr,
                                                       8192, 1024, 4096, 1.0f, 1024, 0);
}